// Round 5
// baseline (712.728 us; speedup 1.0000x reference)
//
#include <hip/hip_runtime.h>
#include <math.h>

// Problem constants (from reference setup_inputs)
constexpr int N  = 8;
constexpr int C  = 32;
constexpr int H  = 256;
constexpr int W  = 256;
constexpr int HU = 512;   // upsampled H
constexpr int WU = 512;   // upsampled W
constexpr int HW  = H * W;
constexpr int HWU = HU * WU;

// Round 5 = round 4 (LDS-staged gather) with the staging bug fixed: the r4
// staging copy moved only 4 of each thread's assigned 16 floats -> 3/4 of
// the LDS tile was garbage (absmax 721). New mapping: 16 lanes cover one
// full 64-float row per instruction (coalesced), 4 row-groups per thread.
// Theory unchanged: kernel is bound by distinct cache lines touched per wave
// (~1-1.5 cyc/line TA/TCP tag path); staging the block-uniform input bbox
// into LDS with coalesced rows cuts line touches 5-8x.
constexpr int TILE = 32;      // 32x32 outputs per 256-thread block
constexpr int SW   = 64;      // staged cols
constexpr int SH   = 64;      // staged rows (max)
constexpr int LST  = 68;      // LDS row stride, floats (272B = 17*16B)

typedef float f4 __attribute__((ext_vector_type(4)));
typedef float f2 __attribute__((ext_vector_type(2)));
typedef f4 f4u __attribute__((aligned(4)));   // dword-aligned 16B access

// Per-axis decomposition of (grid_sample bilinear) o (upsample2x bilinear):
// a continuous coordinate collapses to a 3-consecutive-texel window of the
// ORIGINAL axis with 3 merged weights. base clamped to [0, n_in-3].
struct Axis {
    int   base;
    float w0, w1, w2;
};

__device__ __forceinline__ Axis make_axis(float coord, int n_in, int n_up) {
    float c0f = floorf(coord);
    float t   = coord - c0f;         // grid_sample frac weight
    int   u0  = (int)c0f;            // upsampled-axis corner a

    float w3_0 = 0.f, w3_1 = 0.f, w3_2 = 0.f;
    int rb = 0;

    #pragma unroll
    for (int k = 0; k < 2; ++k) {
        int   yu    = u0 + k;
        float Wc    = (k == 0) ? (1.0f - t) : t;      // grid_sample corner weight
        bool  valid = (yu >= 0) && (yu < n_up);       // zero-padding mask

        // upsample2x source: s = (yu+0.5)/2 - 0.5, clamped >= 0
        float s  = fmaxf(0.5f * (float)yu - 0.25f, 0.0f);
        int   r0 = (int)s;                            // floor (s >= 0)
        r0 = min(r0, n_in - 1);                       // keep in-bounds for wild yu
        float wu = s - (float)r0;
        int   r1 = min(r0 + 1, n_in - 1);

        float w0 = valid ? Wc * (1.0f - wu) : 0.0f;
        float w1 = valid ? Wc * wu          : 0.0f;

        if (k == 0) rb = min(r0, n_in - 3);           // window base from corner a

        int s0 = min(max(r0 - rb, 0), 2);
        int s1 = min(max(r1 - rb, 0), 2);
        w3_0 += (s0 == 0) ? w0 : 0.0f;
        w3_1 += (s0 == 1) ? w0 : 0.0f;
        w3_2 += (s0 == 2) ? w0 : 0.0f;
        w3_0 += (s1 == 0) ? w1 : 0.0f;
        w3_1 += (s1 == 1) ? w1 : 0.0f;
        w3_2 += (s1 == 2) ? w1 : 0.0f;
    }

    Axis ax;
    ax.base = rb;
    ax.w0 = w3_0; ax.w1 = w3_1; ax.w2 = w3_2;
    return ax;
}

// base-only version of make_axis's k=0 window base (monotone in coord, so
// evaluating the 4 tile corners bounds every interior pixel's base).
__device__ __forceinline__ int axis_base(float coord, int n_in) {
    int   u0 = (int)floorf(coord);
    float s  = fmaxf(0.5f * (float)u0 - 0.25f, 0.0f);
    int   r0 = min((int)s, n_in - 1);
    return min(r0, n_in - 3);
}

// 4-wide weight vector aligned to a shared window base: e = base - bl in {0,1}.
__device__ __forceinline__ f4 wvec(const Axis& a, int bl) {
    int e = a.base - bl;
    return e ? f4{0.0f, a.w0, a.w1, a.w2} : f4{a.w0, a.w1, a.w2, 0.0f};
}

__global__ __launch_bounds__(256, 4)
void fused_up_affine_sample(const float* __restrict__ x,
                            const float* __restrict__ theta,
                            float* __restrict__ out) {
    __shared__ float lds[SH * LST];   // 17408 B

    int tid  = threadIdx.x;
    int lane = tid & 63;
    int wv   = tid >> 6;
    int qx   = lane & 15;             // quad col (16 quads wide)
    int qy   = wv * 4 + (lane >> 4);  // quad row (16 quads tall)

    int bx = blockIdx.x * TILE;
    int by = blockIdx.y * TILE;
    int wo = bx + qx * 2;             // output cols wo, wo+1
    int ho = by + qy * 2;             // output rows ho, ho+1
    int n  = blockIdx.z;

    const float* th = theta + n * 6;
    float t0 = th[0], t1 = th[1], t2 = th[2];
    float t3 = th[3], t4 = th[4], t5 = th[5];

    auto coords = [&](float wo_, float ho_, float& ix, float& iy) {
        float gx = (2.0f * wo_ + 1.0f) * (1.0f / (float)WU) - 1.0f;
        float gy = (2.0f * ho_ + 1.0f) * (1.0f / (float)HU) - 1.0f;
        float ox = t0 * gx + t1 * gy + t2;
        float oy = t3 * gx + t4 * gy + t5;
        ix = ((ox + 1.0f) * (float)WU - 1.0f) * 0.5f;
        iy = ((oy + 1.0f) * (float)HU - 1.0f) * 0.5f;
    };

    // Axes for the 4 quad pixels.
    Axis x00, y00, x01, y01, x10, y10, x11, y11;
    { float ix, iy;
      coords((float)wo,       (float)ho,       ix, iy); x00 = make_axis(ix, W, WU); y00 = make_axis(iy, H, HU);
      coords((float)(wo + 1), (float)ho,       ix, iy); x01 = make_axis(ix, W, WU); y01 = make_axis(iy, H, HU);
      coords((float)wo,       (float)(ho + 1), ix, iy); x10 = make_axis(ix, W, WU); y10 = make_axis(iy, H, HU);
      coords((float)(wo + 1), (float)(ho + 1), ix, iy); x11 = make_axis(ix, W, WU); y11 = make_axis(iy, H, HU);
    }

    // Block-uniform input bbox from the 4 tile-corner pixels (affine map is
    // linear in (wo,ho); axis_base is monotone in the coord => corner bases
    // bound all interior pixel bases).
    int cminx, cmaxx, cminy, cmaxy;
    { float ix, iy;
      coords((float)bx,              (float)by,              ix, iy);
      int a0x = axis_base(ix, W), a0y = axis_base(iy, H);
      coords((float)(bx + TILE - 1), (float)by,              ix, iy);
      int a1x = axis_base(ix, W), a1y = axis_base(iy, H);
      coords((float)bx,              (float)(by + TILE - 1), ix, iy);
      int a2x = axis_base(ix, W), a2y = axis_base(iy, H);
      coords((float)(bx + TILE - 1), (float)(by + TILE - 1), ix, iy);
      int a3x = axis_base(ix, W), a3y = axis_base(iy, H);
      cminx = min(min(a0x, a1x), min(a2x, a3x));
      cmaxx = max(max(a0x, a1x), max(a2x, a3x));
      cminy = min(min(a0y, a1y), min(a2y, a3y));
      cmaxy = max(max(a0y, a1y), max(a2y, a3y));
    }
    bool blockfast = ((cmaxx + 4 - cminx) <= SW) && ((cmaxy + 4 - cminy) <= SH);

    const float* xn = x   + (size_t)n * (C * HW);
    float*       on = out + (size_t)n * (C * HWU);

    if (blockfast) {
        // Staged window origin (always fully in-image: gb <= dim-64 >= 0).
        int gbx = min(cminx, W - SW);
        int gby = min(cminy, H - SH);
        int shu = min(cmaxy + 4 - gby, SH);   // rows needed
        int swu = min(cmaxx + 4 - gbx, SW);   // cols needed

        // Staging map: 16 lanes cover one 64-float row (256B contiguous),
        // 4 row-groups per thread. Every assigned float is copied (r4 bug:
        // 16-wide chunks but only 4 floats copied -> garbage LDS).
        int srow = tid >> 4;                  // 0..15
        int scol = (tid & 15) * 4;            // 0..60, 16B-aligned in LDS
        bool cstage = (scol < swu);
        bool rstage[4];
        const float* gsrc[4];
        float* lrow[4];
        #pragma unroll
        for (int g = 0; g < 4; ++g) {
            int r = srow + 16 * g;
            rstage[g] = cstage && (r < shu);
            gsrc[g]   = xn + (gby + r) * W + (gbx + scol);
            lrow[g]   = lds + r * LST + scol;
        }

        // Per-quad shared 4x4 window (tight in ~all quads since upsample2x
        // halves the coordinate rate: base moves ~1 per 2 output px).
        int bminx = min(min(x00.base, x01.base), min(x10.base, x11.base));
        int bmaxx = max(max(x00.base, x01.base), max(x10.base, x11.base));
        int bminy = min(min(y00.base, y01.base), min(y10.base, y11.base));
        int bmaxy = max(max(y00.base, y01.base), max(y10.base, y11.base));
        bool tight = (bmaxx - bminx <= 1) && (bmaxy - bminy <= 1);

        int blx = min(bminx, W - 4);
        int bly = min(bminy, H - 4);
        f4 wx00 = wvec(x00, blx), wx01 = wvec(x01, blx);
        f4 wx10 = wvec(x10, blx), wx11 = wvec(x11, blx);
        f4 wy00 = wvec(y00, bly), wy01 = wvec(y01, bly);
        f4 wy10 = wvec(y10, bly), wy11 = wvec(y11, bly);

        const float* lq = lds + (bly - gby) * LST + (blx - gbx);
        float*       ob = on + ho * WU + wo;

        // Prologue: channel-0 staging loads in flight.
        f4 vc[4] = {};
        #pragma unroll
        for (int g = 0; g < 4; ++g)
            if (rstage[g]) vc[g] = *(const f4u*)gsrc[g];

        for (int c = 0; c < C; ++c) {
            __syncthreads();                 // prior channel's LDS reads done
            #pragma unroll
            for (int g = 0; g < 4; ++g)
                if (rstage[g]) *(f4*)lrow[g] = vc[g];   // aligned ds_write_b128
            __syncthreads();                 // staged tile visible

            // Issue next channel's staging loads NOW: their vmcnt-drain is at
            // the next barrier, covered by this channel's compute.
            f4 vn[4] = {};
            #pragma unroll
            for (int g = 0; g < 4; ++g)
                if (rstage[g] && (c + 1 < C)) vn[g] = *(const f4u*)(gsrc[g] + (c + 1) * HW);

            float* po = ob + c * HWU;
            if (tight) {
                f4 a0 = *(const f4u*)(lq);
                f4 a1 = *(const f4u*)(lq + LST);
                f4 a2 = *(const f4u*)(lq + 2 * LST);
                f4 a3 = *(const f4u*)(lq + 3 * LST);
                auto pxv = [&](const f4& wy, const f4& wx) -> float {
                    f4 acc = a0 * wy.x + a1 * wy.y + a2 * wy.z + a3 * wy.w;
                    return acc.x * wx.x + acc.y * wx.y + acc.z * wx.z + acc.w * wx.w;
                };
                float o00 = pxv(wy00, wx00);
                float o01 = pxv(wy01, wx01);
                float o10 = pxv(wy10, wx10);
                float o11 = pxv(wy11, wx11);
                *(f2*)(po)      = f2{o00, o01};
                *(f2*)(po + WU) = f2{o10, o11};
            } else {
                // Rare loose quad: per-pixel 3x3 from LDS (rows/cols proven
                // inside the staged window under blockfast; f4 spare lane .w
                // stays within the row's 68-float stride).
                auto px1 = [&](const Axis& ax, const Axis& ay) -> float {
                    const float* p = lds + (ay.base - gby) * LST + (ax.base - gbx);
                    f4 r0 = *(const f4u*)(p);
                    f4 r1 = *(const f4u*)(p + LST);
                    f4 r2 = *(const f4u*)(p + 2 * LST);
                    float s0 = r0.x * ax.w0 + r0.y * ax.w1 + r0.z * ax.w2;
                    float s1 = r1.x * ax.w0 + r1.y * ax.w1 + r1.z * ax.w2;
                    float s2 = r2.x * ax.w0 + r2.y * ax.w1 + r2.z * ax.w2;
                    return ay.w0 * s0 + ay.w1 * s1 + ay.w2 * s2;
                };
                *(f2*)(po)      = f2{px1(x00, y00), px1(x01, y01)};
                *(f2*)(po + WU) = f2{px1(x10, y10), px1(x11, y11)};
            }
            #pragma unroll
            for (int g = 0; g < 4; ++g) vc[g] = vn[g];
        }
    } else {
        // Rare block fallback (extreme theta): per-pixel 3x3 global gather.
        #pragma unroll
        for (int i = 0; i < 4; ++i) {
            const Axis& ax = (i == 0) ? x00 : (i == 1) ? x01 : (i == 2) ? x10 : x11;
            const Axis& ay = (i == 0) ? y00 : (i == 1) ? y01 : (i == 2) ? y10 : y11;
            int wo_ = wo + (i & 1);
            int ho_ = ho + (i >> 1);
            const float* pb = xn + ay.base * W + ax.base;
            float*       po = on + ho_ * WU + wo_;
            for (int c = 0; c < C; ++c) {
                const float* p = pb + c * HW;
                float r0 = p[0        ] * ax.w0 + p[1        ] * ax.w1 + p[2        ] * ax.w2;
                float r1 = p[W        ] * ax.w0 + p[W + 1    ] * ax.w1 + p[W + 2    ] * ax.w2;
                float r2 = p[2 * W    ] * ax.w0 + p[2 * W + 1] * ax.w1 + p[2 * W + 2] * ax.w2;
                po[c * HWU] = ay.w0 * r0 + ay.w1 * r1 + ay.w2 * r2;
            }
        }
    }
}

extern "C" void kernel_launch(void* const* d_in, const int* in_sizes, int n_in,
                              void* d_out, int out_size, void* d_ws, size_t ws_size,
                              hipStream_t stream) {
    const float* x     = (const float*)d_in[0];
    const float* theta = (const float*)d_in[1];
    float*       out   = (float*)d_out;

    dim3 grid(WU / TILE, HU / TILE, N);   // 16 x 16 x 8 = 2048 blocks
    fused_up_affine_sample<<<grid, 256, 0, stream>>>(x, theta, out);
}

// Round 6
// 488.751 us; speedup vs baseline: 1.4583x; 1.4583x over previous
//
#include <hip/hip_runtime.h>
#include <math.h>

// Problem constants (from reference setup_inputs)
constexpr int N  = 8;
constexpr int C  = 32;
constexpr int H  = 256;
constexpr int W  = 256;
constexpr int HU = 512;   // upsampled H
constexpr int WU = 512;   // upsampled W
constexpr int HW  = H * W;
constexpr int HWU = HU * WU;

// Round 6: revert LDS staging (r5: FETCH 31->932 MB, WRITE +140 MB, occ 38%
// -> scratch/thrash, 3x regression). Back to r3's global-gather quads, but
// each lane now produces a 2x4 OUTPUT BLOCK (8 px). Because the fused
// base-coordinate rate is |theta|/2 per output px, the 8 pixels' 3-tap
// windows usually share ONE 4x4 input window (per-axis base span <= 1):
//   tier1 (common): 4 loads + 2 f4 stores per 8 px  -> 0.5 load-instr/px
//   tier2 (else):   two 4x4 windows (== r3 cost)    -> 1.0 load-instr/px
//   tier3 (rare):   per-pixel 3x3 scalar fallback
// Tiers are wave-uniform (__all) like r3's quad gate.
typedef float f4 __attribute__((ext_vector_type(4)));
typedef f4 f4u __attribute__((aligned(4)));   // dword-aligned 16B access

// Per-axis decomposition of (grid_sample bilinear) o (upsample2x bilinear):
// a continuous coordinate collapses to a 3-consecutive-texel window of the
// ORIGINAL axis with 3 merged weights. base clamped to [0, n_in-3].
struct Axis {
    int   base;
    float w0, w1, w2;
};

__device__ __forceinline__ Axis make_axis(float coord, int n_in, int n_up) {
    float c0f = floorf(coord);
    float t   = coord - c0f;         // grid_sample frac weight
    int   u0  = (int)c0f;            // upsampled-axis corner a

    float w3_0 = 0.f, w3_1 = 0.f, w3_2 = 0.f;
    int rb = 0;

    #pragma unroll
    for (int k = 0; k < 2; ++k) {
        int   yu    = u0 + k;
        float Wc    = (k == 0) ? (1.0f - t) : t;      // grid_sample corner weight
        bool  valid = (yu >= 0) && (yu < n_up);       // zero-padding mask

        // upsample2x source: s = (yu+0.5)/2 - 0.5, clamped >= 0
        float s  = fmaxf(0.5f * (float)yu - 0.25f, 0.0f);
        int   r0 = (int)s;                            // floor (s >= 0)
        r0 = min(r0, n_in - 1);                       // keep in-bounds for wild yu
        float wu = s - (float)r0;
        int   r1 = min(r0 + 1, n_in - 1);

        float w0 = valid ? Wc * (1.0f - wu) : 0.0f;
        float w1 = valid ? Wc * wu          : 0.0f;

        if (k == 0) rb = min(r0, n_in - 3);           // window base from corner a

        int s0 = min(max(r0 - rb, 0), 2);
        int s1 = min(max(r1 - rb, 0), 2);
        w3_0 += (s0 == 0) ? w0 : 0.0f;
        w3_1 += (s0 == 1) ? w0 : 0.0f;
        w3_2 += (s0 == 2) ? w0 : 0.0f;
        w3_0 += (s1 == 0) ? w1 : 0.0f;
        w3_1 += (s1 == 1) ? w1 : 0.0f;
        w3_2 += (s1 == 2) ? w1 : 0.0f;
    }

    Axis ax;
    ax.base = rb;
    ax.w0 = w3_0; ax.w1 = w3_1; ax.w2 = w3_2;
    return ax;
}

// 4-wide weight vector aligned to a shared window base: e = base - bl in {0,1}.
__device__ __forceinline__ f4 wvec(const Axis& a, int bl) {
    int e = a.base - bl;
    return e ? f4{0.0f, a.w0, a.w1, a.w2} : f4{a.w0, a.w1, a.w2, 0.0f};
}

__global__ __launch_bounds__(128)
void fused_up_affine_sample(const float* __restrict__ x,
                            const float* __restrict__ theta,
                            float* __restrict__ out) {
    int tid  = threadIdx.x;
    int lane = tid & 63;
    int wv   = tid >> 6;               // wave in block (0..1)
    int lx   = lane & 15;              // 4-col unit (0..15)
    int lyw  = lane >> 4;              // 2-row unit within wave (0..3)

    int bx = blockIdx.x * 64;
    int by = blockIdx.y * 16;
    int wo = bx + lx * 4;              // output cols wo..wo+3
    int ho = by + wv * 8 + lyw * 2;    // output rows ho, ho+1
    int n  = blockIdx.z;

    const float* th = theta + n * 6;
    float t0 = th[0], t1 = th[1], t2 = th[2];
    float t3 = th[3], t4 = th[4], t5 = th[5];

    auto coords = [&](float wo_, float ho_, float& ix, float& iy) {
        float gx = (2.0f * wo_ + 1.0f) * (1.0f / (float)WU) - 1.0f;
        float gy = (2.0f * ho_ + 1.0f) * (1.0f / (float)HU) - 1.0f;
        float ox = t0 * gx + t1 * gy + t2;
        float oy = t3 * gx + t4 * gy + t5;
        ix = ((ox + 1.0f) * (float)WU - 1.0f) * 0.5f;
        iy = ((oy + 1.0f) * (float)HU - 1.0f) * 0.5f;
    };

    // Axes for all 8 pixels (ix and iy both depend on col AND row).
    Axis ax[2][4], ay[2][4];
    #pragma unroll
    for (int i = 0; i < 2; ++i) {
        #pragma unroll
        for (int j = 0; j < 4; ++j) {
            float ix, iy;
            coords((float)(wo + j), (float)(ho + i), ix, iy);
            ax[i][j] = make_axis(ix, W, WU);
            ay[i][j] = make_axis(iy, H, HU);
        }
    }

    const float* xn = x   + (size_t)n * (C * HW);
    float*       on = out + (size_t)n * (C * HWU);
    float*       ob = on + ho * WU + wo;

    // ---- tier-1 gate: all 8 pixels share one 4x4 window ----
    int xmn = ax[0][0].base, xmx = xmn, ymn = ay[0][0].base, ymx = ymn;
    #pragma unroll
    for (int i = 0; i < 2; ++i) {
        #pragma unroll
        for (int j = 0; j < 4; ++j) {
            xmn = min(xmn, ax[i][j].base); xmx = max(xmx, ax[i][j].base);
            ymn = min(ymn, ay[i][j].base); ymx = max(ymx, ay[i][j].base);
        }
    }
    bool tight8 = (xmx - xmn <= 1) && (ymx - ymn <= 1);

    if (__all(tight8)) {
        int blx = min(xmn, W - 4);     // window cols blx..blx+3, all in-image
        int bly = min(ymn, H - 4);     // window rows bly..bly+3, all in-image
        f4 wx[2][4], wy[2][4];
        #pragma unroll
        for (int i = 0; i < 2; ++i) {
            #pragma unroll
            for (int j = 0; j < 4; ++j) {
                wx[i][j] = wvec(ax[i][j], blx);
                wy[i][j] = wvec(ay[i][j], bly);
            }
        }
        const float* p0 = xn + bly * W + blx;

        #pragma unroll 4
        for (int c = 0; c < C; ++c) {
            const float* p = p0 + c * HW;
            f4 a0 = *(const f4u*)(p);
            f4 a1 = *(const f4u*)(p + W);
            f4 a2 = *(const f4u*)(p + 2 * W);
            f4 a3 = *(const f4u*)(p + 3 * W);
            float* po = ob + c * HWU;
            #pragma unroll
            for (int i = 0; i < 2; ++i) {
                f4 r;
                #pragma unroll
                for (int j = 0; j < 4; ++j) {
                    f4 acc = a0 * wy[i][j].x + a1 * wy[i][j].y
                           + a2 * wy[i][j].z + a3 * wy[i][j].w;
                    r[j] = acc.x * wx[i][j].x + acc.y * wx[i][j].y
                         + acc.z * wx[i][j].z + acc.w * wx[i][j].w;
                }
                *(f4*)(po + i * WU) = r;   // 16B-aligned (wo % 4 == 0)
            }
        }
        return;
    }

    // ---- tier-2 gate: each 2x2 quad (cols {0,1} / {2,3}) tight ----
    int xmnq[2], xmxq[2], ymnq[2], ymxq[2];
    #pragma unroll
    for (int q = 0; q < 2; ++q) {
        int b00 = ax[0][2*q].base, b01 = ax[0][2*q+1].base;
        int b10 = ax[1][2*q].base, b11 = ax[1][2*q+1].base;
        xmnq[q] = min(min(b00, b01), min(b10, b11));
        xmxq[q] = max(max(b00, b01), max(b10, b11));
        int c00 = ay[0][2*q].base, c01 = ay[0][2*q+1].base;
        int c10 = ay[1][2*q].base, c11 = ay[1][2*q+1].base;
        ymnq[q] = min(min(c00, c01), min(c10, c11));
        ymxq[q] = max(max(c00, c01), max(c10, c11));
    }
    bool tight4 = (xmxq[0] - xmnq[0] <= 1) && (ymxq[0] - ymnq[0] <= 1)
               && (xmxq[1] - xmnq[1] <= 1) && (ymxq[1] - ymnq[1] <= 1);

    if (__all(tight4)) {
        int blxq0 = min(xmnq[0], W - 4), blyq0 = min(ymnq[0], H - 4);
        int blxq1 = min(xmnq[1], W - 4), blyq1 = min(ymnq[1], H - 4);
        f4 wxq[2][2][2], wyq[2][2][2];          // [q][i][jj]
        #pragma unroll
        for (int q = 0; q < 2; ++q) {
            int blx = q ? blxq1 : blxq0;
            int bly = q ? blyq1 : blyq0;
            #pragma unroll
            for (int i = 0; i < 2; ++i) {
                #pragma unroll
                for (int jj = 0; jj < 2; ++jj) {
                    wxq[q][i][jj] = wvec(ax[i][2*q + jj], blx);
                    wyq[q][i][jj] = wvec(ay[i][2*q + jj], bly);
                }
            }
        }
        const float* pA0 = xn + blyq0 * W + blxq0;
        const float* pB0 = xn + blyq1 * W + blxq1;

        #pragma unroll 4
        for (int c = 0; c < C; ++c) {
            const float* pA = pA0 + c * HW;
            const float* pB = pB0 + c * HW;
            f4 A0 = *(const f4u*)(pA);
            f4 A1 = *(const f4u*)(pA + W);
            f4 A2 = *(const f4u*)(pA + 2 * W);
            f4 A3 = *(const f4u*)(pA + 3 * W);
            f4 B0 = *(const f4u*)(pB);
            f4 B1 = *(const f4u*)(pB + W);
            f4 B2 = *(const f4u*)(pB + 2 * W);
            f4 B3 = *(const f4u*)(pB + 3 * W);
            float* po = ob + c * HWU;
            #pragma unroll
            for (int i = 0; i < 2; ++i) {
                f4 r;
                #pragma unroll
                for (int jj = 0; jj < 2; ++jj) {
                    f4 accA = A0 * wyq[0][i][jj].x + A1 * wyq[0][i][jj].y
                            + A2 * wyq[0][i][jj].z + A3 * wyq[0][i][jj].w;
                    r[jj] = accA.x * wxq[0][i][jj].x + accA.y * wxq[0][i][jj].y
                          + accA.z * wxq[0][i][jj].z + accA.w * wxq[0][i][jj].w;
                    f4 accB = B0 * wyq[1][i][jj].x + B1 * wyq[1][i][jj].y
                            + B2 * wyq[1][i][jj].z + B3 * wyq[1][i][jj].w;
                    r[2 + jj] = accB.x * wxq[1][i][jj].x + accB.y * wxq[1][i][jj].y
                              + accB.z * wxq[1][i][jj].z + accB.w * wxq[1][i][jj].w;
                }
                *(f4*)(po + i * WU) = r;
            }
        }
        return;
    }

    // ---- tier-3 fallback (extreme theta): per-pixel 3x3 scalar gather ----
    for (int c = 0; c < C; ++c) {
        #pragma unroll
        for (int i = 0; i < 2; ++i) {
            #pragma unroll
            for (int j = 0; j < 4; ++j) {
                const Axis& axp = ax[i][j];
                const Axis& ayp = ay[i][j];
                const float* p = xn + c * HW + ayp.base * W + axp.base;
                float r0 = p[0        ] * axp.w0 + p[1        ] * axp.w1 + p[2        ] * axp.w2;
                float r1 = p[W        ] * axp.w0 + p[W + 1    ] * axp.w1 + p[W + 2    ] * axp.w2;
                float r2 = p[2 * W    ] * axp.w0 + p[2 * W + 1] * axp.w1 + p[2 * W + 2] * axp.w2;
                on[(size_t)c * HWU + (ho + i) * WU + (wo + j)] =
                    ayp.w0 * r0 + ayp.w1 * r1 + ayp.w2 * r2;
            }
        }
    }
}

extern "C" void kernel_launch(void* const* d_in, const int* in_sizes, int n_in,
                              void* d_out, int out_size, void* d_ws, size_t ws_size,
                              hipStream_t stream) {
    const float* x     = (const float*)d_in[0];
    const float* theta = (const float*)d_in[1];
    float*       out   = (float*)d_out;

    dim3 grid(WU / 64, HU / 16, N);   // 8 x 32 x 8 = 2048 blocks, 128 thr
    fused_up_affine_sample<<<grid, 128, 0, stream>>>(x, theta, out);
}

// Round 7
// 402.725 us; speedup vs baseline: 1.7698x; 1.2136x over previous
//
#include <hip/hip_runtime.h>
#include <math.h>

// Problem constants (from reference setup_inputs)
constexpr int N  = 8;
constexpr int C  = 32;
constexpr int H  = 256;
constexpr int W  = 256;
constexpr int HU = 512;   // upsampled H
constexpr int WU = 512;   // upsampled W
constexpr int HW  = H * W;
constexpr int HWU = HU * WU;

// Round 7 = r3's quad structure (proven ~163us) + the two occupancy/latency
// fixes r6 inverted:
//  - VGPR cap: __launch_bounds__(128,4) keeps waves/SIMD >= 4 (r6: 160 VGPR
//    -> 9.7% occupancy -> 270us on identical memory work).
//  - Register double-buffer over channels with sched_barrier(0) pinning the
//    prefetch ABOVE the compute (r2 showed the compiler re-sinks loads to
//    their uses otherwise): steady-state 8 loads in flight/wave, consumed at
//    vmcnt(4) instead of vmcnt(0)-per-channel. Kernel is latency-bound
//    (VALUBusy 12-17%, issue-accounting ~10% of duration).
typedef float f4 __attribute__((ext_vector_type(4)));
typedef float f2 __attribute__((ext_vector_type(2)));
typedef f4 f4u __attribute__((aligned(4)));   // dword-aligned 16B access

// Per-axis decomposition of (grid_sample bilinear) o (upsample2x bilinear):
// a continuous coordinate collapses to a 3-consecutive-texel window of the
// ORIGINAL axis with 3 merged weights. base clamped to [0, n_in-3].
struct Axis {
    int   base;
    float w0, w1, w2;
};

__device__ __forceinline__ Axis make_axis(float coord, int n_in, int n_up) {
    float c0f = floorf(coord);
    float t   = coord - c0f;         // grid_sample frac weight
    int   u0  = (int)c0f;            // upsampled-axis corner a

    float w3_0 = 0.f, w3_1 = 0.f, w3_2 = 0.f;
    int rb = 0;

    #pragma unroll
    for (int k = 0; k < 2; ++k) {
        int   yu    = u0 + k;
        float Wc    = (k == 0) ? (1.0f - t) : t;      // grid_sample corner weight
        bool  valid = (yu >= 0) && (yu < n_up);       // zero-padding mask

        // upsample2x source: s = (yu+0.5)/2 - 0.5, clamped >= 0
        float s  = fmaxf(0.5f * (float)yu - 0.25f, 0.0f);
        int   r0 = (int)s;                            // floor (s >= 0)
        r0 = min(r0, n_in - 1);                       // keep in-bounds for wild yu
        float wu = s - (float)r0;
        int   r1 = min(r0 + 1, n_in - 1);

        float w0 = valid ? Wc * (1.0f - wu) : 0.0f;
        float w1 = valid ? Wc * wu          : 0.0f;

        if (k == 0) rb = min(r0, n_in - 3);           // window base from corner a

        int s0 = min(max(r0 - rb, 0), 2);
        int s1 = min(max(r1 - rb, 0), 2);
        w3_0 += (s0 == 0) ? w0 : 0.0f;
        w3_1 += (s0 == 1) ? w0 : 0.0f;
        w3_2 += (s0 == 2) ? w0 : 0.0f;
        w3_0 += (s1 == 0) ? w1 : 0.0f;
        w3_1 += (s1 == 1) ? w1 : 0.0f;
        w3_2 += (s1 == 2) ? w1 : 0.0f;
    }

    Axis ax;
    ax.base = rb;
    ax.w0 = w3_0; ax.w1 = w3_1; ax.w2 = w3_2;
    return ax;
}

// 4-wide weight vector aligned to a shared window base: e = base - bl in {0,1}
// (e = 2 impossible: bases cap at n-3, so blx = n-4 clamp gives e <= 1).
__device__ __forceinline__ f4 wvec(const Axis& a, int bl) {
    int e = a.base - bl;
    return e ? f4{0.0f, a.w0, a.w1, a.w2} : f4{a.w0, a.w1, a.w2, 0.0f};
}

__global__ __launch_bounds__(128, 4)
void fused_up_affine_sample(const float* __restrict__ x,
                            const float* __restrict__ theta,
                            float* __restrict__ out) {
    int tid  = threadIdx.x;
    int lane = tid & 63;
    int wv   = tid >> 6;                     // wave id in block (0..1)
    int lx   = lane & 31;                    // col-pair index within wave
    int ly   = lane >> 5;                    // row-pair index within wave

    int wo = blockIdx.x * 64 + lx * 2;       // output cols wo, wo+1
    int ho = blockIdx.y * 8 + wv * 4 + ly * 2; // output rows ho, ho+1
    int n  = blockIdx.z;

    const float* th = theta + n * 6;
    float t0 = th[0], t1 = th[1], t2 = th[2];
    float t3 = th[3], t4 = th[4], t5 = th[5];

    // Axes for the 4 quad pixels (ix AND iy both depend on col and row).
    Axis x00, y00, x01, y01, x10, y10, x11, y11;
    auto pix = [&](int wo_, int ho_, Axis& axx, Axis& axy) {
        float gx = (2.0f * (float)wo_ + 1.0f) * (1.0f / (float)WU) - 1.0f;
        float gy = (2.0f * (float)ho_ + 1.0f) * (1.0f / (float)HU) - 1.0f;
        float ox = t0 * gx + t1 * gy + t2;
        float oy = t3 * gx + t4 * gy + t5;
        float ix = ((ox + 1.0f) * (float)WU - 1.0f) * 0.5f;
        float iy = ((oy + 1.0f) * (float)HU - 1.0f) * 0.5f;
        axx = make_axis(ix, W, WU);
        axy = make_axis(iy, H, HU);
    };
    pix(wo,     ho,     x00, y00);
    pix(wo + 1, ho,     x01, y01);
    pix(wo,     ho + 1, x10, y10);
    pix(wo + 1, ho + 1, x11, y11);

    int bminx = min(min(x00.base, x01.base), min(x10.base, x11.base));
    int bmaxx = max(max(x00.base, x01.base), max(x10.base, x11.base));
    int bminy = min(min(y00.base, y01.base), min(y10.base, y11.base));
    int bmaxy = max(max(y00.base, y01.base), max(y10.base, y11.base));
    bool ok = (bmaxx - bminx <= 1) && (bmaxy - bminy <= 1);

    const float* xn = x   + (size_t)n * (C * HW);
    float*       on = out + (size_t)n * (C * HWU);

    if (!__any(!ok)) {
        // ---- fast path: one 4x4 window serves the whole quad ----
        int blx = min(bminx, W - 4);         // window fully in-image
        int bly = min(bminy, H - 4);

        f4 wx00 = wvec(x00, blx), wx01 = wvec(x01, blx);
        f4 wx10 = wvec(x10, blx), wx11 = wvec(x11, blx);
        f4 wy00 = wvec(y00, bly), wy01 = wvec(y01, bly);
        f4 wy10 = wvec(y10, bly), wy11 = wvec(y11, bly);

        const float* p0 = xn + bly * W + blx;
        float*       ob = on + ho * WU + wo;

        f4 A0, A1, A2, A3, B0, B1, B2, B3;   // named double-buffer (rule #20)
        auto ld = [&](f4& d0, f4& d1, f4& d2, f4& d3, int c) {
            const float* p = p0 + c * HW;
            d0 = *(const f4u*)(p);
            d1 = *(const f4u*)(p + W);
            d2 = *(const f4u*)(p + 2 * W);
            d3 = *(const f4u*)(p + 3 * W);
        };
        auto st = [&](const f4& a0, const f4& a1, const f4& a2, const f4& a3,
                      int c) {
            auto pxv = [&](const f4& wy, const f4& wx) -> float {
                f4 acc = a0 * wy.x + a1 * wy.y + a2 * wy.z + a3 * wy.w;
                return acc.x * wx.x + acc.y * wx.y + acc.z * wx.z + acc.w * wx.w;
            };
            float* po = ob + c * HWU;
            *(f2*)(po)      = f2{pxv(wy00, wx00), pxv(wy01, wx01)};
            *(f2*)(po + WU) = f2{pxv(wy10, wx10), pxv(wy11, wx11)};
        };

        ld(A0, A1, A2, A3, 0);               // prologue
        #pragma unroll
        for (int c = 0; c < C; c += 2) {
            // issue c+1's loads BEFORE consuming c; barrier stops the
            // scheduler from sinking them below the compute (r2 failure).
            ld(B0, B1, B2, B3, c + 1);       // c+1 <= 31 always (C even)
            __builtin_amdgcn_sched_barrier(0);
            st(A0, A1, A2, A3, c);
            if (c + 2 < C) ld(A0, A1, A2, A3, c + 2);
            __builtin_amdgcn_sched_barrier(0);
            st(B0, B1, B2, B3, c + 1);
        }
    } else {
        // ---- rare fallback (extreme theta): per-pixel 3x3 scalar gather ----
        #pragma unroll
        for (int i = 0; i < 4; ++i) {
            const Axis& axp = (i == 0) ? x00 : (i == 1) ? x01 : (i == 2) ? x10 : x11;
            const Axis& ayp = (i == 0) ? y00 : (i == 1) ? y01 : (i == 2) ? y10 : y11;
            int wo_ = wo + (i & 1);
            int ho_ = ho + (i >> 1);
            const float* pb = xn + ayp.base * W + axp.base;
            float*       po = on + ho_ * WU + wo_;
            for (int c = 0; c < C; ++c) {
                const float* p = pb + c * HW;
                float r0 = p[0        ] * axp.w0 + p[1        ] * axp.w1 + p[2        ] * axp.w2;
                float r1 = p[W        ] * axp.w0 + p[W + 1    ] * axp.w1 + p[W + 2    ] * axp.w2;
                float r2 = p[2 * W    ] * axp.w0 + p[2 * W + 1] * axp.w1 + p[2 * W + 2] * axp.w2;
                po[c * HWU] = ayp.w0 * r0 + ayp.w1 * r1 + ayp.w2 * r2;
            }
        }
    }
}

extern "C" void kernel_launch(void* const* d_in, const int* in_sizes, int n_in,
                              void* d_out, int out_size, void* d_ws, size_t ws_size,
                              hipStream_t stream) {
    const float* x     = (const float*)d_in[0];
    const float* theta = (const float*)d_in[1];
    float*       out   = (float*)d_out;

    dim3 grid(WU / 64, HU / 8, N);   // 8 x 64 x 8 = 4096 blocks, 128 thr
    fused_up_affine_sample<<<grid, 128, 0, stream>>>(x, theta, out);
}